// Round 5
// baseline (327.353 us; speedup 1.0000x reference)
//
#include <hip/hip_runtime.h>
#include <math.h>

// SingleRoIExtractor: 4-level FPN RoIAlign (mmdet legacy, aligned=False)
// R5: HYBRID. Evidence R0-R4: LDS-staged structure (R1, 155us) saturates the
// per-CU LDS pipe (~350cy/block-channel, ~1/8 transaction load); pure-gather
// structure (R3, 149us) saturates the per-CU VMEM transaction path
// (~350cy/block-channel, zero LDS). Two independent per-CU pipes, each worth
// ~150us alone -> split blocks 50/50 between the two PROVEN paths so both
// pipes run concurrently on every CU. Type = (blockIdx.x+blockIdx.y)&1 so
// x-fastest dispatch order interleaves types across CUs/time.
//   path G (gather, R3 verbatim): wave w owns channels w,w+4,..., lane=bin,
//     16 scalar corner loads/channel straight from global, no LDS/barriers.
//   path S (staged, R1 verbatim): ring-2 LDS buffers, depth-4 register
//     prefetch, one __syncthreads per channel, float4->ds_write_b128 staging.
// Both paths previously passed the harness standalone; per-(k,g) output is
// produced by exactly one path.
// Diagnostic: if this lands ~150us the pipes share a hidden limiter.

#define OUT_SZ 7
#define NCH 256
#define NBINS 49
#define CGC 64
#define NGROUPS 4
#define LDS_N 1920

// ======================= path S: staged (R1 verbatim) ======================
template<int VSH>
__device__ __forceinline__ void roi_group(
    const float* __restrict__ cbase, int CLrel, int HW, int H, int W,
    float x1, float y1, float bw, float bh,
    int t, float* __restrict__ outk, float (*lds)[LDS_N])
{
    const int V = 1 << VSH;
    const float fH = (float)H, fW = (float)W;

    float xf0 = fminf(fmaxf(x1 + 0.25f * bw, 0.0f), fW - 1.0f);
    float xfl = fminf(fmaxf(x1 + 6.75f * bw, 0.0f), fW - 1.0f);
    int xa = (int)floorf(xf0);
    int xb = min((int)floorf(xfl) + 1, W - 1);
    float yf0 = fminf(fmaxf(y1 + 0.25f * bh, 0.0f), fH - 1.0f);
    float yfl = fminf(fmaxf(y1 + 6.75f * bh, 0.0f), fH - 1.0f);
    int ya = (int)floorf(yf0);
    int yb = min((int)floorf(yfl) + 1, H - 1);

    int axa    = xa & ~(V - 1);            // aligned col base
    int cpr    = ((xb - axa) >> VSH) + 1;  // chunks per row
    int rowlen = cpr << VSH;
    int stride = rowlen + (((rowlen & 31) == 0) ? V : 0);
    int Rows   = yb - ya + 1;
    int C      = Rows * cpr;               // total chunks

    {   // zero sentinel + pad (targets of weight-0 overrun reads)
        int sent = Rows * stride;          // <= ~1704 < LDS_N
        if (t == 0) { lds[0][sent] = 0.0f; lds[1][sent] = 0.0f; }
        int padw = stride - rowlen;
        if (padw) {
            int np = Rows * padw;
            for (int z = t; z < np; z += 256) {
                int zr = z / padw, zc = z - zr * padw;
                int idx = zr * stride + rowlen + zc;
                lds[0][idx] = 0.0f;
                lds[1][idx] = 0.0f;
            }
        }
    }

    int q0 = (t + 60) & 255;
    int goff[2], loff[2];
    bool act[2];
#pragma unroll
    for (int i = 0; i < 2; ++i) {
        int q = q0 + 256 * i;
        act[i] = q < C;
        int qq = act[i] ? q : 0;
        int r  = qq / cpr;
        int j  = qq - r * cpr;
        int rowbase = (ya + r) * W;
        int rel  = rowbase + axa + (j << VSH);
        int relc = min(rel, CLrel);        // tensor-end clamp, V-aligned
        goff[i] = relc;
        loff[i] = r * stride + (relc - rowbase - axa);
    }

    int bin = t >> 2;
    int s   = t & 3;
    int oy  = bin / OUT_SZ;
    int ox  = bin - oy * OUT_SZ;

    float xs  = x1 + ((float)(2 * ox + (s & 1)) + 0.5f) * 0.5f * bw;
    float ysv = y1 + ((float)(2 * oy + (s >> 1)) + 0.5f) * 0.5f * bh;
    bool vall = (xs >= -1.0f) && (xs <= fW) && (ysv >= -1.0f) && (ysv <= fH);

    float xc = fminf(fmaxf(xs, 0.0f), fW - 1.0f);
    float yc = fminf(fmaxf(ysv, 0.0f), fH - 1.0f);
    float xflr = floorf(xc), yflr = floorf(yc);
    int x0 = (int)xflr, y0 = (int)yflr;
    float lx = xc - xflr, ly = yc - yflr;

    int p0 = (y0 - ya) * stride + (x0 - axa);
    int ry = min(y0 + 1 - ya, Rows - 1);
    int p1 = ry * stride + (x0 - axa);

    float w00 = (1.0f - ly) * (1.0f - lx);
    float w01 = (1.0f - ly) * lx;
    float w10 = ly * (1.0f - lx);
    float w11 = ly * lx;

    auto ldchunk = [&](const float* p, int i) -> float4 {
        if (!act[i]) return make_float4(0.f, 0.f, 0.f, 0.f);
        if (VSH == 2) return *(const float4*)(p + goff[i]);
        float2 h2 = *(const float2*)(p + goff[i]);
        return make_float4(h2.x, h2.y, 0.f, 0.f);
    };
    auto stchunk = [&](float* dst, int i, float4 v) {
        if (act[i]) {
            if (VSH == 2) *(float4*)(dst + loff[i]) = v;
            else          *(float2*)(dst + loff[i]) = make_float2(v.x, v.y);
        }
    };

    float4 pv0[2], pv1[2], pv2[2], pv3[2], t0[2];
    t0[0]  = ldchunk(cbase, 0);
    pv1[0] = ldchunk(cbase + (size_t)HW, 0);
    pv2[0] = ldchunk(cbase + 2 * (size_t)HW, 0);
    pv3[0] = ldchunk(cbase + 3 * (size_t)HW, 0);
    pv0[0] = ldchunk(cbase + 4 * (size_t)HW, 0);
    if (C > 256) {
        t0[1]  = ldchunk(cbase, 1);
        pv1[1] = ldchunk(cbase + (size_t)HW, 1);
        pv2[1] = ldchunk(cbase + 2 * (size_t)HW, 1);
        pv3[1] = ldchunk(cbase + 3 * (size_t)HW, 1);
        pv0[1] = ldchunk(cbase + 4 * (size_t)HW, 1);
    }
    stchunk(lds[0], 0, t0[0]);
    if (C > 256) stchunk(lds[0], 1, t0[1]);
    __syncthreads();

#define ITER(kk, PV)                                                    \
    {                                                                   \
        const int c = cc + (kk);                                        \
        if (c + 1 < CGC) {                                              \
            float* dst = lds[((kk) + 1) & 1];                           \
            stchunk(dst, 0, PV[0]);                                     \
            if (C > 256) stchunk(dst, 1, PV[1]);                        \
        }                                                               \
        if (c + 5 < CGC) {                                              \
            const float* pn = cbase + (size_t)(c + 5) * HW;             \
            PV[0] = ldchunk(pn, 0);                                     \
            if (C > 256) PV[1] = ldchunk(pn, 1);                        \
        }                                                               \
        if (t < 196) {                                                  \
            const float* L = lds[(kk) & 1];                             \
            float v00 = L[p0];                                          \
            float v01 = L[p0 + 1];                                      \
            float v10 = L[p1];                                          \
            float v11 = L[p1 + 1];                                      \
            float val = vall ? (v00 * w00 + v01 * w01 + v10 * w10 +     \
                                v11 * w11)                              \
                             : 0.0f;                                    \
            val += __shfl_xor(val, 1, 64);                              \
            val += __shfl_xor(val, 2, 64);                              \
            if (s == 0) outk[c * NBINS + bin] = val * 0.25f;            \
        }                                                               \
        __syncthreads();                                                \
    }

    for (int cc = 0; cc < CGC; cc += 4) {
        ITER(0, pv1)
        ITER(1, pv2)
        ITER(2, pv3)
        ITER(3, pv0)
    }
#undef ITER
}

// ======================= path G: gather (R3 verbatim) ======================
__device__ __forceinline__ void roi_gather_direct(
    const float* __restrict__ cbase, float* __restrict__ outk,
    int HW, int H, int W,
    float x1, float y1, float bw, float bh, int t)
{
    const int w    = t >> 6;   // wave id 0..3
    const int lane = t & 63;
    const float fH = (float)H, fW = (float)W;

    if (lane >= NBINS) return;   // no barriers in this path -> safe
    const int bin = lane;
    const int oy = bin / OUT_SZ;
    const int ox = bin - oy * OUT_SZ;

    float lx[2], fvx[2]; int cx[2];
#pragma unroll
    for (int j = 0; j < 2; ++j) {
        float xs = x1 + ((float)(2 * ox + j) + 0.5f) * 0.5f * bw;
        fvx[j] = (xs >= -1.0f && xs <= fW) ? 1.0f : 0.0f;
        float xc = fminf(fmaxf(xs, 0.0f), fW - 1.0f);
        int x0 = (int)floorf(xc);
        x0 = min(x0, W - 2);            // xc=W-1 -> lx=1.0 selects col W-1
        lx[j] = xc - (float)x0;
        cx[j] = x0;
    }
    float ly[2], fvy[2]; int ry[2];
#pragma unroll
    for (int i = 0; i < 2; ++i) {
        float ysv = y1 + ((float)(2 * oy + i) + 0.5f) * 0.5f * bh;
        fvy[i] = (ysv >= -1.0f && ysv <= fH) ? 1.0f : 0.0f;
        float yc = fminf(fmaxf(ysv, 0.0f), fH - 1.0f);
        int y0 = (int)floorf(yc);
        y0 = min(y0, H - 2);            // yc=H-1 -> ly=1.0 selects row H-1
        ly[i] = yc - (float)y0;
        ry[i] = y0;
    }
    float wv00 = fvy[0] * fvx[0], wv01 = fvy[0] * fvx[1];
    float wv10 = fvy[1] * fvx[0], wv11 = fvy[1] * fvx[1];

    int off[8];
#pragma unroll
    for (int r = 0; r < 4; ++r) {
        int row = ry[r >> 1] + (r & 1);
        off[2 * r + 0] = row * W + cx[0];
        off[2 * r + 1] = row * W + cx[1];
    }

    const float* chp = cbase + (size_t)w * HW;
    float* outp = outk + (size_t)w * NBINS + bin;

#pragma unroll 2
    for (int i = 0; i < 16; ++i) {      // channels w, w+4, ..., w+60
        float v0[8], v1[8];
#pragma unroll
        for (int q = 0; q < 8; ++q) {
            v0[q] = chp[off[q]];
            v1[q] = chp[off[q] + 1];
        }
        float h[8];
#pragma unroll
        for (int q = 0; q < 8; ++q)
            h[q] = fmaf(lx[q & 1], v1[q] - v0[q], v0[q]);   // x-interp

        float s00 = fmaf(ly[0], h[2] - h[0], h[0]);
        float s01 = fmaf(ly[0], h[3] - h[1], h[1]);
        float s10 = fmaf(ly[1], h[6] - h[4], h[4]);
        float s11 = fmaf(ly[1], h[7] - h[5], h[5]);

        float acc = wv00 * s00 + wv01 * s01 + wv10 * s10 + wv11 * s11;
        *outp = acc * 0.25f;

        chp  += 4 * (size_t)HW;
        outp += 4 * NBINS;
    }
}

// ================================ kernel ==================================
__global__ __launch_bounds__(256, 8)
void roi_align_hybrid(const float* __restrict__ f0, const float* __restrict__ f1,
                      const float* __restrict__ f2, const float* __restrict__ f3,
                      const float* __restrict__ rois,
                      float* __restrict__ out)
{
    __shared__ __align__(16) float lds[2][LDS_N];

    const int k = blockIdx.x;
    const int g = blockIdx.y;
    const int t = threadIdx.x;

    float rb   = rois[k * 5 + 0];
    float rix1 = rois[k * 5 + 1];
    float riy1 = rois[k * 5 + 2];
    float rix2 = rois[k * 5 + 3];
    float riy2 = rois[k * 5 + 4];

    float scale = sqrtf((rix2 - rix1 + 1.0f) * (riy2 - riy1 + 1.0f));
    int lvl = (int)floorf(log2f(scale * (1.0f / 56.0f) + 1e-6f));
    lvl = lvl < 0 ? 0 : (lvl > 3 ? 3 : lvl);

    float ss = 1.0f / (float)(4 << lvl);
    float x1 = rix1 * ss, y1 = riy1 * ss;
    float rw = fmaxf(rix2 * ss - x1, 1.0f);
    float rh = fmaxf(riy2 * ss - y1, 1.0f);
    float bw = rw * (1.0f / OUT_SZ);
    float bh = rh * (1.0f / OUT_SZ);
    const int H = 800  >> (2 + lvl);
    const int W = 1216 >> (2 + lvl);

    const float* fb = (lvl == 0) ? f0 : (lvl == 1) ? f1 : (lvl == 2) ? f2 : f3;
    const int HW  = H * W;
    const int TOT = 2 * NCH * HW;
    const int base_off = ((int)rb * NCH + g * CGC) * HW;
    const float* cbase = fb + base_off;
    float* outk = out + ((size_t)k * NCH + (size_t)(g * CGC)) * NBINS;

    if (((k + g) & 1) == 0) {
        // ---- path G: direct gather (transaction pipe) ----
        roi_gather_direct(cbase, outk, HW, H, W, x1, y1, bw, bh, t);
    } else {
        // ---- path S: LDS-staged (LDS pipe) ----
        if (W & 3) {   // level 3 (W=38): only 8B alignment -> float2 chunks
            int CLrel = TOT - base_off - (CGC - 1) * HW - 2;
            roi_group<1>(cbase, CLrel, HW, H, W, x1, y1, bw, bh, t, outk, lds);
        } else {       // levels 0-2: 16B-aligned float4 chunks
            int CLrel = TOT - base_off - (CGC - 1) * HW - 4;
            roi_group<2>(cbase, CLrel, HW, H, W, x1, y1, bw, bh, t, outk, lds);
        }
    }
}

extern "C" void kernel_launch(void* const* d_in, const int* in_sizes, int n_in,
                              void* d_out, int out_size, void* d_ws, size_t ws_size,
                              hipStream_t stream)
{
    const float* f0   = (const float*)d_in[0];
    const float* f1   = (const float*)d_in[1];
    const float* f2   = (const float*)d_in[2];
    const float* f3   = (const float*)d_in[3];
    const float* rois = (const float*)d_in[4];
    float* out = (float*)d_out;

    int K = in_sizes[4] / 5;
    if (K <= 0) return;

    roi_align_hybrid<<<dim3(K, NGROUPS), 256, 0, stream>>>(f0, f1, f2, f3, rois, out);
}

// Round 7
// 319.645 us; speedup vs baseline: 1.0241x; 1.0241x over previous
//
#include <hip/hip_runtime.h>
#include <math.h>

// SingleRoIExtractor: 4-level FPN RoIAlign (mmdet legacy, aligned=False)
// R7 (= R6 resubmit; R6 bench was an infra failure, not a kernel result).
// Evidence R0-R5: five structurally different kernels (staged / deep
// prefetch / no-drain barrier / gather / separable / hybrid) ALL land
// 149-175us moving ~365-400MB of beyond-L2 fetch at a pinned 2.5-3.0 TB/s;
// dur*BW conserved across structures -> the scattered-64B-line fetch stream
// IS the limiter, and FETCH == sum of per-roi patch bytes (~360KB/roi) ==
// zero cross-roi reuse. Overlap exists (lvl0 patch sum ~3x plane size); it
// is wasted because consecutive blocks are random rois on random XCDs and
// L2 (4MB) turns over in ~12us. Fix: dispatch 1 sorts rois by (image,
// level, Morton-of-patch-center) in one block (bitonic, LDS, perm -> d_ws);
// dispatch 2 is the R3 gather body verbatim with
// k = perm[xcd_chunked(blockIdx.x)] (bijective m204 chunking: each XCD gets
// a contiguous run of sorted order, so concurrent blocks per XCD are
// spatial neighbors sharing L2 lines).
// Prediction: FETCH 380 -> 180-260MB, main kernel 149 -> 90-120us.

#define OUT_SZ 7
#define NCH 256
#define NBINS 49
#define NGROUPS 4
#define SORT_N 2048          // bitonic capacity (pad to pow2); K=1024 here

// ============================ dispatch 1: sort ============================
__global__ __launch_bounds__(256, 8)
void roi_sort_kernel(const float* __restrict__ rois, int K, int N,
                     int* __restrict__ perm)
{
    __shared__ unsigned long long s[SORT_N];
    const int t = threadIdx.x;

    for (int i = t; i < N; i += 256) {
        unsigned key = 0xFFFFFFFFu;           // pad entries sort to the end
        if (i < K) {
            float rb = rois[i * 5 + 0];
            float x1 = rois[i * 5 + 1], y1 = rois[i * 5 + 2];
            float x2 = rois[i * 5 + 3], y2 = rois[i * 5 + 4];
            float scale = sqrtf((x2 - x1 + 1.0f) * (y2 - y1 + 1.0f));
            int lvl = (int)floorf(log2f(scale * (1.0f / 56.0f) + 1e-6f));
            lvl = lvl < 0 ? 0 : (lvl > 3 ? 3 : lvl);
            float ss = 1.0f / (float)(4 << lvl);
            float Wf = 1216.0f * ss, Hf = 800.0f * ss;
            float cx = 0.5f * (x1 + x2) * ss;
            float cy = 0.5f * (y1 + y2) * ss;
            float qxf = cx * (128.0f / Wf);
            float qyf = cy * (128.0f / Hf);
            // NaN-safe clamp to [0,127]
            int qx = (int)fminf(fmaxf(qxf, 0.0f), 127.0f);
            int qy = (int)fminf(fmaxf(qyf, 0.0f), 127.0f);
            unsigned m = 0;
#pragma unroll
            for (int bb = 0; bb < 7; ++bb)
                m |= (((unsigned)(qx >> bb) & 1u) << (2 * bb)) |
                     (((unsigned)(qy >> bb) & 1u) << (2 * bb + 1));
            unsigned img = (rb > 0.5f) ? 1u : 0u;
            key = (((img * 4u + (unsigned)lvl) << 14) | m);
        }
        s[i] = ((unsigned long long)key << 32) | (unsigned)i;
    }
    __syncthreads();

    for (int size = 2; size <= N; size <<= 1) {
        for (int stride = size >> 1; stride > 0; stride >>= 1) {
            for (int tid = t; tid < N / 2; tid += 256) {
                int lo = tid & (stride - 1);
                int i = ((tid - lo) << 1) + lo;
                int j = i + stride;
                bool asc = ((i & size) == 0);
                unsigned long long a = s[i], b = s[j];
                if ((a > b) == asc) { s[i] = b; s[j] = a; }
            }
            __syncthreads();
        }
    }

    for (int i = t; i < K; i += 256)
        perm[i] = (int)(unsigned)(s[i] & 0xFFFFFFFFu);
}

// ===================== dispatch 2: gather (R3 verbatim) ====================
__global__ __launch_bounds__(256, 6)
void roi_align_direct(const float* __restrict__ f0, const float* __restrict__ f1,
                      const float* __restrict__ f2, const float* __restrict__ f3,
                      const float* __restrict__ rois,
                      const int* __restrict__ perm, int K,
                      float* __restrict__ out)
{
    // XCD-chunked bijective remap (m204): consecutive sorted indices stay on
    // one XCD (blocks dispatch round-robin: xcd ~ blockIdx.x % 8).
    int k;
    {
        const int orig = blockIdx.x;
        const int q = K >> 3, r = K & 7;
        const int xcd = orig & 7, pos = orig >> 3;
        int idx = (xcd < r ? xcd * (q + 1) : r * (q + 1) + (xcd - r) * q) + pos;
        k = perm ? perm[idx] : idx;
    }
    const int g = blockIdx.y;
    const int t = threadIdx.x;
    const int w    = t >> 6;   // wave id 0..3
    const int lane = t & 63;

    float rb   = rois[k * 5 + 0];
    float rix1 = rois[k * 5 + 1];
    float riy1 = rois[k * 5 + 2];
    float rix2 = rois[k * 5 + 3];
    float riy2 = rois[k * 5 + 4];

    float scale = sqrtf((rix2 - rix1 + 1.0f) * (riy2 - riy1 + 1.0f));
    int lvl = (int)floorf(log2f(scale * (1.0f / 56.0f) + 1e-6f));
    lvl = lvl < 0 ? 0 : (lvl > 3 ? 3 : lvl);

    float ss = 1.0f / (float)(4 << lvl);
    float x1 = rix1 * ss, y1 = riy1 * ss;
    float rw = fmaxf(rix2 * ss - x1, 1.0f);
    float rh = fmaxf(riy2 * ss - y1, 1.0f);
    float bw = rw * (1.0f / OUT_SZ);
    float bh = rh * (1.0f / OUT_SZ);
    const int H = 800  >> (2 + lvl);
    const int W = 1216 >> (2 + lvl);
    const float fH = (float)H, fW = (float)W;
    const float* fb = (lvl == 0) ? f0 : (lvl == 1) ? f1 : (lvl == 2) ? f2 : f3;
    const int HW = H * W;

    if (lane >= NBINS) return;   // no barriers anywhere -> early exit is safe
    const int bin = lane;
    const int oy = bin / OUT_SZ;
    const int ox = bin - oy * OUT_SZ;

    // ---- per-lane sample geometry (computed once, reused for 16 channels) ----
    float lx[2], fvx[2]; int cx[2];
#pragma unroll
    for (int j = 0; j < 2; ++j) {
        float xs = x1 + ((float)(2 * ox + j) + 0.5f) * 0.5f * bw;
        fvx[j] = (xs >= -1.0f && xs <= fW) ? 1.0f : 0.0f;
        float xc = fminf(fmaxf(xs, 0.0f), fW - 1.0f);
        int x0 = (int)floorf(xc);
        x0 = min(x0, W - 2);            // xc=W-1 -> lx=1.0 selects col W-1
        lx[j] = xc - (float)x0;
        cx[j] = x0;
    }
    float ly[2], fvy[2]; int ry[2];
#pragma unroll
    for (int i = 0; i < 2; ++i) {
        float ysv = y1 + ((float)(2 * oy + i) + 0.5f) * 0.5f * bh;
        fvy[i] = (ysv >= -1.0f && ysv <= fH) ? 1.0f : 0.0f;
        float yc = fminf(fmaxf(ysv, 0.0f), fH - 1.0f);
        int y0 = (int)floorf(yc);
        y0 = min(y0, H - 2);            // yc=H-1 -> ly=1.0 selects row H-1
        ly[i] = yc - (float)y0;
        ry[i] = y0;
    }
    float wv00 = fvy[0] * fvx[0], wv01 = fvy[0] * fvx[1];
    float wv10 = fvy[1] * fvx[0], wv11 = fvy[1] * fvx[1];

    // 8 element offsets: rows {ry0, ry0+1, ry1, ry1+1} x cols {cx0, cx1}.
    int off[8];
#pragma unroll
    for (int r = 0; r < 4; ++r) {
        int row = ry[r >> 1] + (r & 1);
        off[2 * r + 0] = row * W + cx[0];
        off[2 * r + 1] = row * W + cx[1];
    }

    const int ch0 = g * 64 + w;         // this wave's first channel
    const float* chp = fb + (size_t)((int)rb * NCH + ch0) * HW;
    float* outp = out + ((size_t)k * NCH + ch0) * NBINS + bin;

#pragma unroll 2
    for (int i = 0; i < 16; ++i) {      // channels ch0, ch0+4, ..., ch0+60
        float v0[8], v1[8];
#pragma unroll
        for (int q = 0; q < 8; ++q) {
            v0[q] = chp[off[q]];
            v1[q] = chp[off[q] + 1];
        }
        float h[8];
#pragma unroll
        for (int q = 0; q < 8; ++q)
            h[q] = fmaf(lx[q & 1], v1[q] - v0[q], v0[q]);   // x-interp

        float s00 = fmaf(ly[0], h[2] - h[0], h[0]);
        float s01 = fmaf(ly[0], h[3] - h[1], h[1]);
        float s10 = fmaf(ly[1], h[6] - h[4], h[4]);
        float s11 = fmaf(ly[1], h[7] - h[5], h[5]);

        float acc = wv00 * s00 + wv01 * s01 + wv10 * s10 + wv11 * s11;
        *outp = acc * 0.25f;

        chp  += 4 * (size_t)HW;
        outp += 4 * NBINS;
    }
}

// ================================ launch ==================================
extern "C" void kernel_launch(void* const* d_in, const int* in_sizes, int n_in,
                              void* d_out, int out_size, void* d_ws, size_t ws_size,
                              hipStream_t stream)
{
    const float* f0   = (const float*)d_in[0];
    const float* f1   = (const float*)d_in[1];
    const float* f2   = (const float*)d_in[2];
    const float* f3   = (const float*)d_in[3];
    const float* rois = (const float*)d_in[4];
    float* out = (float*)d_out;

    int K = in_sizes[4] / 5;
    if (K <= 0) return;

    int* perm = nullptr;
    if (K <= SORT_N && d_ws && ws_size >= (size_t)K * sizeof(int)) {
        perm = (int*)d_ws;
        int N = 1;
        while (N < K) N <<= 1;          // pad to pow2 (<= SORT_N)
        roi_sort_kernel<<<1, 256, 0, stream>>>(rois, K, N, perm);
    }

    roi_align_direct<<<dim3(K, NGROUPS), 256, 0, stream>>>(
        f0, f1, f2, f3, rois, perm, K, out);
}